// Round 1
// baseline (129.003 us; speedup 1.0000x reference)
//
#include <hip/hip_runtime.h>
#include <math.h>

#define BINS 10

// Problem constants: BATCH=8388608, NUM_CLASSES=2
constexpr float NTOT_F = 16777216.0f;   // BATCH * NUM_CLASSES

constexpr int G1      = 2048;
constexpr int BLK     = 256;
constexpr int NTHREAD = G1 * BLK;             // 524288
constexpr int NWAVES  = NTHREAD / 64;         // 8192 global waves
constexpr int ITERS   = 4;                    // 2 quads/iter * 4 = 8 quads/thread
                                              // = NPAIRS(4194304)/NTHREAD exactly

constexpr int SLOTS = 19;   // 0..8 = P_1..P_9, 9 = sumL (=P_0), 10..18 = N_1..N_9

// Workspace: arr[slot*G1 + block] f32 = 19*2048*4 = 155648 B
constexpr size_t WS_ARR = 0;

// Native clang vectors so __builtin_nontemporal_load works (HIP float4 is a
// struct, not a vector type).
typedef float f4 __attribute__((ext_vector_type(4)));
typedef int   i2 __attribute__((ext_vector_type(2)));

// Prefix thresholds: bin>=i  <=>  g = t/(1+t) >= i/9.9999  <=>  t >= T_i,
// T_i = i/(9.9999-i) (host-computed in double, stored fp32).
__constant__ const float TH[9] = {
    0.11111234569273214f,   // 1/8.9999
    0.25000312503906297f,   // 2/7.9999
    0.42857755110787297f,   // 3/6.9999
    0.66667777796296605f,   // 4/5.9999
    1.00002000040000800f,   // 5/4.9999
    1.50003750093752340f,   // 6/3.9999
    2.33341111370379013f,   // 7/2.9999
    4.00020001000050002f,   // 8/1.9999
    9.00090009000900090f    // 9/0.9999
};

// Hot-path ledger (main-kernel µs): LDS f32 atomics 92 (R4), fused+device-fence
// 180 (R8), ballot/popc 44 (R7), LDS RMW 37 (R2/3), VGPR cndmask 28-30 (R5/R9),
// threshold-prefix ~25 (R10 -- BEST math, total 117.3). R11 (shuffle-tree
// epilogue) and R12 (z-compares + pk_fma) regressed. R13 (this): keep R10 math
// verbatim; fix the MEMORY pipeline instead -- dense lane->quad remap (all 4
// loads/iter perfectly coalesced: 2x dwordx4 x at 16B/lane stride-16, 2x int2 t
// at 8B/lane), nontemporal hints (read-once stream), __launch_bounds__(256,8)
// to pin 64-VGPR / 32-wave/CU occupancy (LDS 19456B*8 = 152KiB fits 160KiB).
__device__ __forceinline__ void proc(float x, bool y1,
                                     float* __restrict__ P, float& sumL,
                                     unsigned* __restrict__ N) {
    // z = (y==1) ? -x : x ; t = e^z ; bce = ln(1+t) = ln2*log2(1+t)
    float z = y1 ? -x : x;
    float t = __builtin_amdgcn_exp2f(z * 1.4426950408889634f);
    float u = 1.0f + t;
    float l = __builtin_amdgcn_logf(u);  // log2(u); ln2 applied once at the end
    sumL += l;                           // P_0
#pragma unroll
    for (int i = 0; i < BINS - 1; ++i) {
        bool hit = t >= TH[i];           // one v_cmp, shared by both accumulates
        P[i] += hit ? l : 0.0f;          // v_cndmask + v_add
        N[i] += hit ? 1u : 0u;           // v_addc
    }
}

__global__ __launch_bounds__(BLK, 8) void ghm_main(const f4* __restrict__ x4,
                                                   const i2* __restrict__ t2,
                                                   float*    __restrict__ arr) {
    const int tid  = threadIdx.x;
    const int lane = tid & 63;
    const int wave = tid >> 6;
    const int gw   = blockIdx.x * (BLK / 64) + wave;   // global wave id, 0..8191

    float P[BINS - 1];
    unsigned N[BINS - 1];
#pragma unroll
    for (int b = 0; b < BINS - 1; ++b) { P[b] = 0.0f; N[b] = 0u; }
    float sumL = 0.0f;

    // Each wave covers 128 consecutive x-quads per iter; lane l takes quads
    // Q+l and Q+64+l. Every load instruction is a dense, aligned segment:
    // x: 64 lanes x 16B = 1KB contiguous; t: 64 lanes x 8B = 512B contiguous.
    // (Old pattern was 16B loads on a 32B stride -> 2KB span, granules touched
    // twice per pair.) t2[q] = int2(target[2q], target[2q+1]) matches x-quad q
    // = (x[2q][0], x[2q][1], x[2q+1][0], x[2q+1][1]).
#pragma unroll
    for (int k = 0; k < ITERS; ++k) {
        const int Q  = (gw + k * NWAVES) * 128;
        const int q1 = Q + lane;
        const int q2 = q1 + 64;
        f4 xa = __builtin_nontemporal_load(x4 + q1);
        f4 xb = __builtin_nontemporal_load(x4 + q2);
        i2 ta = __builtin_nontemporal_load(t2 + q1);
        i2 tb = __builtin_nontemporal_load(t2 + q2);
        proc(xa[0], ta[0] == 0, P, sumL, N);
        proc(xa[1], ta[0] == 1, P, sumL, N);
        proc(xa[2], ta[1] == 0, P, sumL, N);
        proc(xa[3], ta[1] == 1, P, sumL, N);
        proc(xb[0], tb[0] == 0, P, sumL, N);
        proc(xb[1], tb[0] == 1, P, sumL, N);
        proc(xb[2], tb[1] == 0, P, sumL, N);
        proc(xb[3], tb[1] == 1, P, sumL, N);
    }

    // ---- block reduce through conflict-free LDS columns (19 slots) ----
    __shared__ float cols[SLOTS * BLK];   // 19456 B
#pragma unroll
    for (int b = 0; b < BINS - 1; ++b) cols[b * BLK + tid] = P[b];
    cols[9 * BLK + tid] = sumL;
#pragma unroll
    for (int b = 0; b < BINS - 1; ++b)
        cols[(10 + b) * BLK + tid] = (float)N[b];   // <=32 -> exact in f32
    __syncthreads();

    // wave w reduces slots {w, w+4, ...}: 4 strided reads + 6-step shuffle tree
    for (int s = wave; s < SLOTS; s += 4) {
        float v = cols[s * BLK + lane]       + cols[s * BLK + lane + 64]
                + cols[s * BLK + lane + 128] + cols[s * BLK + lane + 192];
        for (int off = 32; off > 0; off >>= 1) v += __shfl_down(v, off, 64);
        if (lane == 0) arr[s * G1 + blockIdx.x] = v;   // slot-major for final
    }
}

// Final: 10 waves; wave w reduces slots {w, w+10}. Prefix->bin via adjacent
// differences in f64; thread 0 forms beta per reference fp32 arithmetic and
// writes the mean. Deterministic.
__global__ __launch_bounds__(640) void ghm_final(const float* __restrict__ arr,
                                                 float*       __restrict__ out) {
    const int wave = threadIdx.x >> 6;   // 0..9
    const int lane = threadIdx.x & 63;
    __shared__ double Red[SLOTS];
    for (int s = wave; s < SLOTS; s += 10) {
        double v = 0.0;
#pragma unroll
        for (int k = 0; k < G1 / 64; ++k) v += (double)arr[s * G1 + k * 64 + lane];
        for (int off = 32; off > 0; off >>= 1) v += __shfl_down(v, off, 64);
        if (lane == 0) Red[s] = v;
    }
    __syncthreads();
    if (threadIdx.x == 0) {
        // prefix arrays: Pp[0]=sumL, Pp[1..9]=Red[0..8], Pp[10]=0; same for counts
        double Pp[BINS + 1], Np[BINS + 1];
        Pp[0] = Red[9];            Np[0] = (double)NTOT_F;
#pragma unroll
        for (int i = 1; i <= 9; ++i) { Pp[i] = Red[i - 1]; Np[i] = Red[9 + i]; }
        Pp[10] = 0.0; Np[10] = 0.0;

        double Sb[BINS], Cb[BINS];
#pragma unroll
        for (int b = 0; b < BINS; ++b) {
            Sb[b] = Pp[b] - Pp[b + 1];
            Cb[b] = Np[b] - Np[b + 1];
        }
        float nonempty = 0.0f;
#pragma unroll
        for (int b = 0; b < BINS; ++b) nonempty += (Cb[b] > 0.0) ? 1.0f : 0.0f;
        double tot = 0.0;
#pragma unroll
        for (int b = 0; b < BINS; ++b) {
            float gd   = fmaxf((float)Cb[b] * nonempty, 0.0001f);  // ref fp32 math
            float beta = NTOT_F / gd;
            tot += (double)beta * Sb[b];
        }
        // bce sums kept in log2; apply ln2 once, then mean
        out[0] = (float)(tot * 0.693147180559945309 / (double)NTOT_F);
    }
}

extern "C" void kernel_launch(void* const* d_in, const int* in_sizes, int n_in,
                              void* d_out, int out_size, void* d_ws, size_t ws_size,
                              hipStream_t stream) {
    const f4* x4 = (const f4*)d_in[0];   // [B,2] fp32 -> 2 rows per float4
    const i2* t2 = (const i2*)d_in[1];   // int32 targets -> 2 rows per int2

    float* arr = (float*)((char*)d_ws + WS_ARR);
    float* out = (float*)d_out;

    ghm_main <<<G1, BLK, 0, stream>>>(x4, t2, arr);
    ghm_final<<<1, 640, 0, stream>>>(arr, out);
}

// Round 2
// 122.337 us; speedup vs baseline: 1.0545x; 1.0545x over previous
//
#include <hip/hip_runtime.h>
#include <math.h>

#define BINS 10

// Problem constants: BATCH=8388608, NUM_CLASSES=2
constexpr float NTOT_F = 16777216.0f;   // BATCH * NUM_CLASSES

constexpr int G1      = 4096;
constexpr int BLK     = 256;
constexpr int NTHREAD = G1 * BLK;             // 1048576
constexpr int NWAVES  = NTHREAD / 64;         // 16384 global waves
constexpr int ITERS   = 2;                    // 2 quads/iter * 2 = 4 quads/thread
                                              // = NPAIRS(4194304)/NTHREAD exactly

constexpr int SLOTS = 19;   // 0..8 = P_1..P_9, 9 = sumL (=P_0), 10..18 = N_1..N_9

// Workspace: arr[slot*G1 + block] f32 = 19*4096*4 = 311296 B
constexpr size_t WS_ARR = 0;

// Native clang vectors (vector loads, no NT hints -- R13 post-mortem).
typedef float f4 __attribute__((ext_vector_type(4)));
typedef int   i2 __attribute__((ext_vector_type(2)));

// Prefix thresholds: bin>=i  <=>  g = t/(1+t) >= i/9.9999  <=>  t >= T_i,
// T_i = i/(9.9999-i) (host-computed in double, stored fp32).
__constant__ const float TH[9] = {
    0.11111234569273214f,   // 1/8.9999
    0.25000312503906297f,   // 2/7.9999
    0.42857755110787297f,   // 3/6.9999
    0.66667777796296605f,   // 4/5.9999
    1.00002000040000800f,   // 5/4.9999
    1.50003750093752340f,   // 6/3.9999
    2.33341111370379013f,   // 7/2.9999
    4.00020001000050002f,   // 8/1.9999
    9.00090009000900090f    // 9/0.9999
};

// Hot-path ledger (main-kernel µs): LDS f32 atomics 92 (R4), fused+device-fence
// 180 (R8), ballot/popc 44 (R7), LDS RMW 37 (R2/3), VGPR cndmask 28-30 (R5/R9),
// threshold-prefix ~25 (R10 -- BEST math, total 117.3). R11/R12 regressed.
// R13 (remap + NT + 64-VGPR cap at ITERS=4): total 129.0 -- cap with 4 unrolled
// iterations' load state (~70 regs wanted) serialized/spilled. R14 (this):
// keep R10 math + dense remap, DROP NT, and make the 64-VGPR / 8-block/CU
// occupancy target structurally cheap: ITERS=2, G1=4096 (in-flight load regs
// ~24 instead of ~48; est. total ~58 VGPR). LDS 19456B*8 = 152KiB <= 160KiB.
__device__ __forceinline__ void proc(float x, bool y1,
                                     float* __restrict__ P, float& sumL,
                                     unsigned* __restrict__ N) {
    // z = (y==1) ? -x : x ; t = e^z ; bce = ln(1+t) = ln2*log2(1+t)
    float z = y1 ? -x : x;
    float t = __builtin_amdgcn_exp2f(z * 1.4426950408889634f);
    float u = 1.0f + t;
    float l = __builtin_amdgcn_logf(u);  // log2(u); ln2 applied once at the end
    sumL += l;                           // P_0
#pragma unroll
    for (int i = 0; i < BINS - 1; ++i) {
        bool hit = t >= TH[i];           // one v_cmp, shared by both accumulates
        P[i] += hit ? l : 0.0f;          // v_cndmask + v_add
        N[i] += hit ? 1u : 0u;           // v_addc
    }
}

__global__ __launch_bounds__(BLK, 8) void ghm_main(const f4* __restrict__ x4,
                                                   const i2* __restrict__ t2,
                                                   float*    __restrict__ arr) {
    const int tid  = threadIdx.x;
    const int lane = tid & 63;
    const int wave = tid >> 6;
    const int gw   = blockIdx.x * (BLK / 64) + wave;   // global wave id

    float P[BINS - 1];
    unsigned N[BINS - 1];
#pragma unroll
    for (int b = 0; b < BINS - 1; ++b) { P[b] = 0.0f; N[b] = 0u; }
    float sumL = 0.0f;

    // Dense lane->quad remap: each wave covers 128 consecutive x-quads per
    // iter; lane l takes quads Q+l and Q+64+l. Every load instruction is a
    // dense aligned segment: x: 64 lanes x 16B = 1KB contiguous; t: 64 lanes
    // x 8B = 512B contiguous. t2[q] = (target[2q], target[2q+1]) matches
    // x-quad q = (x[2q][0], x[2q][1], x[2q+1][0], x[2q+1][1]).
#pragma unroll
    for (int k = 0; k < ITERS; ++k) {
        const int Q  = (gw + k * NWAVES) * 128;
        const int q1 = Q + lane;
        const int q2 = q1 + 64;
        f4 xa = x4[q1];
        f4 xb = x4[q2];
        i2 ta = t2[q1];
        i2 tb = t2[q2];
        proc(xa[0], ta[0] == 0, P, sumL, N);
        proc(xa[1], ta[0] == 1, P, sumL, N);
        proc(xa[2], ta[1] == 0, P, sumL, N);
        proc(xa[3], ta[1] == 1, P, sumL, N);
        proc(xb[0], tb[0] == 0, P, sumL, N);
        proc(xb[1], tb[0] == 1, P, sumL, N);
        proc(xb[2], tb[1] == 0, P, sumL, N);
        proc(xb[3], tb[1] == 1, P, sumL, N);
    }

    // ---- block reduce through conflict-free LDS columns (19 slots) ----
    __shared__ float cols[SLOTS * BLK];   // 19456 B
#pragma unroll
    for (int b = 0; b < BINS - 1; ++b) cols[b * BLK + tid] = P[b];
    cols[9 * BLK + tid] = sumL;
#pragma unroll
    for (int b = 0; b < BINS - 1; ++b)
        cols[(10 + b) * BLK + tid] = (float)N[b];   // small ints -> exact in f32
    __syncthreads();

    // wave w reduces slots {w, w+4, ...}: 4 strided reads + 6-step shuffle tree
    for (int s = wave; s < SLOTS; s += 4) {
        float v = cols[s * BLK + lane]       + cols[s * BLK + lane + 64]
                + cols[s * BLK + lane + 128] + cols[s * BLK + lane + 192];
        for (int off = 32; off > 0; off >>= 1) v += __shfl_down(v, off, 64);
        if (lane == 0) arr[s * G1 + blockIdx.x] = v;   // slot-major for final
    }
}

// Final: 10 waves; wave w reduces slots {w, w+10}. Prefix->bin via adjacent
// differences in f64; thread 0 forms beta per reference fp32 arithmetic and
// writes the mean. Deterministic.
__global__ __launch_bounds__(640) void ghm_final(const float* __restrict__ arr,
                                                 float*       __restrict__ out) {
    const int wave = threadIdx.x >> 6;   // 0..9
    const int lane = threadIdx.x & 63;
    __shared__ double Red[SLOTS];
    for (int s = wave; s < SLOTS; s += 10) {
        double v = 0.0;
#pragma unroll
        for (int k = 0; k < G1 / 64; ++k) v += (double)arr[s * G1 + k * 64 + lane];
        for (int off = 32; off > 0; off >>= 1) v += __shfl_down(v, off, 64);
        if (lane == 0) Red[s] = v;
    }
    __syncthreads();
    if (threadIdx.x == 0) {
        // prefix arrays: Pp[0]=sumL, Pp[1..9]=Red[0..8], Pp[10]=0; same for counts
        double Pp[BINS + 1], Np[BINS + 1];
        Pp[0] = Red[9];            Np[0] = (double)NTOT_F;
#pragma unroll
        for (int i = 1; i <= 9; ++i) { Pp[i] = Red[i - 1]; Np[i] = Red[9 + i]; }
        Pp[10] = 0.0; Np[10] = 0.0;

        double Sb[BINS], Cb[BINS];
#pragma unroll
        for (int b = 0; b < BINS; ++b) {
            Sb[b] = Pp[b] - Pp[b + 1];
            Cb[b] = Np[b] - Np[b + 1];
        }
        float nonempty = 0.0f;
#pragma unroll
        for (int b = 0; b < BINS; ++b) nonempty += (Cb[b] > 0.0) ? 1.0f : 0.0f;
        double tot = 0.0;
#pragma unroll
        for (int b = 0; b < BINS; ++b) {
            float gd   = fmaxf((float)Cb[b] * nonempty, 0.0001f);  // ref fp32 math
            float beta = NTOT_F / gd;
            tot += (double)beta * Sb[b];
        }
        // bce sums kept in log2; apply ln2 once, then mean
        out[0] = (float)(tot * 0.693147180559945309 / (double)NTOT_F);
    }
}

extern "C" void kernel_launch(void* const* d_in, const int* in_sizes, int n_in,
                              void* d_out, int out_size, void* d_ws, size_t ws_size,
                              hipStream_t stream) {
    const f4* x4 = (const f4*)d_in[0];   // [B,2] fp32 -> 2 rows per float4
    const i2* t2 = (const i2*)d_in[1];   // int32 targets -> 2 rows per int2

    float* arr = (float*)((char*)d_ws + WS_ARR);
    float* out = (float*)d_out;

    ghm_main <<<G1, BLK, 0, stream>>>(x4, t2, arr);
    ghm_final<<<1, 640, 0, stream>>>(arr, out);
}

// Round 3
// 118.497 us; speedup vs baseline: 1.0887x; 1.0324x over previous
//
#include <hip/hip_runtime.h>
#include <math.h>

#define BINS 10

// Problem constants: BATCH=8388608, NUM_CLASSES=2
constexpr int   NPAIRS = 4194304;       // float4 quads (2 rows x 2 classes each)
constexpr float NTOT_F = 16777216.0f;   // BATCH * NUM_CLASSES

constexpr int G1      = 2048;
constexpr int BLK     = 256;
constexpr int NTHREAD = G1 * BLK;             // 524288
constexpr int NCHUNK  = NPAIRS / 2;           // 2097152 chunks of 2 quads (8 el)
constexpr int ITERS   = NCHUNK / NTHREAD;     // 4 exact -> 32 el/thread

constexpr int SLOTS = 19;   // 0..8 = P_1..P_9, 9 = sumL (=P_0), 10..18 = N_1..N_9

// Workspace: arr[slot*G1 + block] f32 = 19*2048*4 = 155648 B
constexpr size_t WS_ARR = 0;

typedef float f4 __attribute__((ext_vector_type(4)));

// Prefix thresholds: bin>=i  <=>  g = t/(1+t) >= i/9.9999  <=>  t >= T_i,
// T_i = i/(9.9999-i) (host-computed in double, stored fp32).
__constant__ const float TH[9] = {
    0.11111234569273214f,   // 1/8.9999
    0.25000312503906297f,   // 2/7.9999
    0.42857755110787297f,   // 3/6.9999
    0.66667777796296605f,   // 4/5.9999
    1.00002000040000800f,   // 5/4.9999
    1.50003750093752340f,   // 6/3.9999
    2.33341111370379013f,   // 7/2.9999
    4.00020001000050002f,   // 8/1.9999
    9.00090009000900090f    // 9/0.9999
};

// Ledger (total µs): R10 threshold-prefix champion 117.3. R11/R12 (epilogue /
// z-compare variants) regressed. R13 (dense remap + NT + 64-VGPR cap, ITERS=4)
// 129.0. R14 (remap + cap, ITERS=2, G1=4096) 122.3. Post-mortem: memory-side
// theories falsified -- R10's strided pair-loads only cost L1 re-passes, and
// occupancy was never the limit. Dispatch accounting: 2x41µs harness poison
// fills + ~1 memset + main ~25 + final ~6 + gaps ~4 = 117. Main's overage vs
// its 16.2µs read floor is mostly dirty-L2 poison evictions (harness-fixed).
// R15 (this): main reverted BYTE-EXACT to R10; final vectorized (float4 loads,
// 16 waves) to cut ~3µs. If this lands ~114-115 we are at the practical floor.
__device__ __forceinline__ void proc(float x, bool y1,
                                     float* __restrict__ P, float& sumL,
                                     unsigned* __restrict__ N) {
    // z = (y==1) ? -x : x ; t = e^z ; bce = ln(1+t) = ln2*log2(1+t)
    float z = y1 ? -x : x;
    float t = __builtin_amdgcn_exp2f(z * 1.4426950408889634f);
    float u = 1.0f + t;
    float l = __builtin_amdgcn_logf(u);  // log2(u); ln2 applied once at the end
    sumL += l;                           // P_0
#pragma unroll
    for (int i = 0; i < BINS - 1; ++i) {
        bool hit = t >= TH[i];           // one v_cmp, shared by both accumulates
        P[i] += hit ? l : 0.0f;          // v_cndmask + v_add
        N[i] += hit ? 1u : 0u;           // v_addc
    }
}

__global__ __launch_bounds__(BLK) void ghm_main(const float4* __restrict__ x4,
                                                const int4*   __restrict__ t4,
                                                float*        __restrict__ arr) {
    const int tid  = threadIdx.x;
    const int lane = tid & 63;
    const int wave = tid >> 6;

    float P[BINS - 1];
    unsigned N[BINS - 1];
#pragma unroll
    for (int b = 0; b < BINS - 1; ++b) { P[b] = 0.0f; N[b] = 0u; }
    float sumL = 0.0f;

    // chunk c covers quads {2c, 2c+1}: two dwordx4 x-loads + one dwordx4 t-load
    const int cbase = blockIdx.x * BLK + tid;
#pragma unroll
    for (int k = 0; k < ITERS; ++k) {
        int c = cbase + k * NTHREAD;
        float4 xa = x4[2 * c];
        float4 xb = x4[2 * c + 1];
        int4   tv = t4[c];
        // element (row, cls): y = (target[row] == cls)
        proc(xa.x, tv.x == 0, P, sumL, N);
        proc(xa.y, tv.x == 1, P, sumL, N);
        proc(xa.z, tv.y == 0, P, sumL, N);
        proc(xa.w, tv.y == 1, P, sumL, N);
        proc(xb.x, tv.z == 0, P, sumL, N);
        proc(xb.y, tv.z == 1, P, sumL, N);
        proc(xb.z, tv.w == 0, P, sumL, N);
        proc(xb.w, tv.w == 1, P, sumL, N);
    }

    // ---- block reduce through conflict-free LDS columns (19 slots) ----
    __shared__ float cols[SLOTS * BLK];   // 19456 B
#pragma unroll
    for (int b = 0; b < BINS - 1; ++b) cols[b * BLK + tid] = P[b];
    cols[9 * BLK + tid] = sumL;
#pragma unroll
    for (int b = 0; b < BINS - 1; ++b)
        cols[(10 + b) * BLK + tid] = (float)N[b];   // <=32 -> exact in f32
    __syncthreads();

    // wave w reduces slots {w, w+4, ...}: 4 strided reads + 6-step shuffle tree
    for (int s = wave; s < SLOTS; s += 4) {
        float v = cols[s * BLK + lane]       + cols[s * BLK + lane + 64]
                + cols[s * BLK + lane + 128] + cols[s * BLK + lane + 192];
        for (int off = 32; off > 0; off >>= 1) v += __shfl_down(v, off, 64);
        if (lane == 0) arr[s * G1 + blockIdx.x] = v;   // slot-major for final
    }
}

// Final: 1024 threads / 16 waves; wave w reduces slots {w, w+16} (only waves
// 0-2 take a second slot). Loads vectorized: each lane reads 8 independent
// float4 (G1/4 = 512 = 8*64), so the per-slot load chain is one latency
// round-trip instead of 32 sequential dwords. f64 accumulation; prefix->bin
// via adjacent differences; thread 0 forms beta per reference fp32 arithmetic
// and writes the mean. Deterministic.
__global__ __launch_bounds__(1024) void ghm_final(const float* __restrict__ arr,
                                                  float*       __restrict__ out) {
    const int wave = threadIdx.x >> 6;   // 0..15
    const int lane = threadIdx.x & 63;
    const f4* arr4 = (const f4*)arr;     // arr is 16B-aligned (ws base)
    __shared__ double Red[SLOTS];
    for (int s = wave; s < SLOTS; s += 16) {
        double v = 0.0;
#pragma unroll
        for (int k = 0; k < G1 / 256; ++k) {     // 8 independent f4 loads
            f4 a = arr4[s * (G1 / 4) + k * 64 + lane];
            v += (double)a[0] + (double)a[1] + (double)a[2] + (double)a[3];
        }
        for (int off = 32; off > 0; off >>= 1) v += __shfl_down(v, off, 64);
        if (lane == 0) Red[s] = v;
    }
    __syncthreads();
    if (threadIdx.x == 0) {
        // prefix arrays: Pp[0]=sumL, Pp[1..9]=Red[0..8], Pp[10]=0; same for counts
        double Pp[BINS + 1], Np[BINS + 1];
        Pp[0] = Red[9];            Np[0] = (double)NTOT_F;
#pragma unroll
        for (int i = 1; i <= 9; ++i) { Pp[i] = Red[i - 1]; Np[i] = Red[9 + i]; }
        Pp[10] = 0.0; Np[10] = 0.0;

        double Sb[BINS], Cb[BINS];
#pragma unroll
        for (int b = 0; b < BINS; ++b) {
            Sb[b] = Pp[b] - Pp[b + 1];
            Cb[b] = Np[b] - Np[b + 1];
        }
        float nonempty = 0.0f;
#pragma unroll
        for (int b = 0; b < BINS; ++b) nonempty += (Cb[b] > 0.0) ? 1.0f : 0.0f;
        double tot = 0.0;
#pragma unroll
        for (int b = 0; b < BINS; ++b) {
            float gd   = fmaxf((float)Cb[b] * nonempty, 0.0001f);  // ref fp32 math
            float beta = NTOT_F / gd;
            tot += (double)beta * Sb[b];
        }
        // bce sums kept in log2; apply ln2 once, then mean
        out[0] = (float)(tot * 0.693147180559945309 / (double)NTOT_F);
    }
}

extern "C" void kernel_launch(void* const* d_in, const int* in_sizes, int n_in,
                              void* d_out, int out_size, void* d_ws, size_t ws_size,
                              hipStream_t stream) {
    const float4* x4 = (const float4*)d_in[0];   // [B,2] fp32 -> 2 rows per float4
    const int4*   t4 = (const int4*)d_in[1];     // int32 targets -> 4 rows per int4

    float* arr = (float*)((char*)d_ws + WS_ARR);
    float* out = (float*)d_out;

    ghm_main <<<G1, BLK, 0, stream>>>(x4, t4, arr);
    ghm_final<<<1, 1024, 0, stream>>>(arr, out);
}